// Round 5
// baseline (2320.577 us; speedup 1.0000x reference)
//
#include <hip/hip_runtime.h>

typedef float v2f __attribute__((ext_vector_type(2)));
typedef float v4f __attribute__((ext_vector_type(4)));

#define HH 30
#define DIN 4
#define KP 32   // k padded to 32 (weights for k>=30 are 0; LDS pads stay 0)

__device__ __forceinline__ float sigf(float v) {
    return __builtin_amdgcn_rcpf(1.0f + __expf(-v));
}
__device__ __forceinline__ v2f fma2(v2f a, v2f b, v2f c) {
    return __builtin_elementwise_fma(a, b, c);
}
__device__ __forceinline__ v2f splat2(float s) { return (v2f)s; }
__device__ __forceinline__ v2f tanh_c2(v2f c) {   // tanh(c) = 2*sig(2c)-1
    return (v2f){fmaf(2.0f, sigf(2.0f * c.x), -1.0f),
                 fmaf(2.0f, sigf(2.0f * c.y), -1.0f)};
}
__device__ __forceinline__ v2f shfl32_v2(v2f v) {
    v2f r;
    r.x = __shfl_xor(v.x, 32, 64);
    r.y = __shfl_xor(v.y, 32, 64);
    return r;
}

// DPP half-wave (32-lane) sum, VALU-pipe only (proven in R4):
template <int Ctrl, int RowMask>
__device__ __forceinline__ float dpp_step(float x) {
    union { float f; int i; } in, out;
    in.f = x;
    out.i = __builtin_amdgcn_update_dpp(0, in.i, Ctrl, RowMask, 0xf, false);
    return x + out.f;
}
__device__ __forceinline__ float half_reduce(float x) {
    x = dpp_step<0x111, 0xf>(x);   // row_shr:1
    x = dpp_step<0x112, 0xf>(x);   // row_shr:2
    x = dpp_step<0x114, 0xf>(x);   // row_shr:4
    x = dpp_step<0x118, 0xf>(x);   // row_shr:8
    x = dpp_step<0x142, 0xa>(x);   // row_bcast:15 -> rows 1,3; lane31/63 = half-sum
    return x;
}

// One wave per block, TWO batch elements per wave, 1 wave/SIMD.
// R4 evidence: at 2 waves/SIMD (256-reg budget) the ~188 weight floats/lane
// get a-spilled to AGPRs -> ~270 extra v_accvgpr VALU ops/step (VGPR=120,
// 418 VALU inst/step measured). Fix: waves_per_eu(1,1) -> 512-reg budget,
// weights fully VGPR-resident; recover parallelism by packing 2 elements
// into the v2f lanes (weights SHARED across elements - same 188 scalars).
// Lane (a = lane>>5, h = lane&31): owns gate rows r0=(2a)*30+h, r1=r0+30
// of both layers, for both elements. Accumulators/multipliers are
// (elem0, elem1) pairs; LDS h-vectors stored element-interleaved [k][e] so
// ds_read_b128 yields two packed multipliers directly. Head reduced via DPP.
__global__ __attribute__((amdgpu_flat_work_group_size(64, 64),
                          amdgpu_waves_per_eu(1, 1)))
void lstm2_kernel(const float* __restrict__ x,
                  const float* __restrict__ Wih1, const float* __restrict__ bih1,
                  const float* __restrict__ Whh1, const float* __restrict__ bhh1,
                  const float* __restrict__ Wih2, const float* __restrict__ bih2,
                  const float* __restrict__ Whh2, const float* __restrict__ bhh2,
                  const float* __restrict__ Wlin, const float* __restrict__ blin,
                  float* __restrict__ out, int T)
{
    const int tid = threadIdx.x;
    const int a = tid >> 5;
    const int h = tid & 31;
    const bool act = (h < HH);
    const int hc = act ? h : (HH - 1);
    const int r0 = (2 * a) * HH + hc;
    const int r1 = (2 * a + 1) * HH + hc;
    const int b0 = blockIdx.x * 2;
    const int b1 = b0 + 1;

    // element-interleaved h vectors: sh[2*k+e]; floats 60..63 stay 0 (k pads)
    __shared__ __align__(16) float sh1[2 * KP];
    __shared__ __align__(16) float sh2[2 * KP];

    // ---- per-lane weights (scalars; shared across both elements) ----
    float wx0[DIN], wx1[DIN];
    float w1r0[KP], w1r1[KP], wi0[KP], wi1[KP], wh0[KP], wh1_[KP];
#pragma unroll
    for (int c = 0; c < DIN; ++c) {
        wx0[c] = Wih1[r0 * DIN + c];
        wx1[c] = Wih1[r1 * DIN + c];
    }
#pragma unroll
    for (int k = 0; k < KP; ++k) {
        const bool ok = (k < HH);
        w1r0[k] = ok ? Whh1[r0 * HH + k] : 0.0f;
        w1r1[k] = ok ? Whh1[r1 * HH + k] : 0.0f;
        wi0[k]  = ok ? Wih2[r0 * HH + k] : 0.0f;
        wi1[k]  = ok ? Wih2[r1 * HH + k] : 0.0f;
        wh0[k]  = ok ? Whh2[r0 * HH + k] : 0.0f;
        wh1_[k] = ok ? Whh2[r1 * HH + k] : 0.0f;
    }
    const float b1r0 = bih1[r0] + bhh1[r0];
    const float b1r1 = bih1[r1] + bhh1[r1];
    const float b2r0 = bih2[r0] + bhh2[r0];
    const float b2r1 = bih2[r1] + bhh2[r1];
    const float wlo0 = act ? Wlin[(2 * a) * HH + hc] : 0.0f;       // output 2a
    const float wlo1 = act ? Wlin[(2 * a + 1) * HH + hc] : 0.0f;   // output 2a+1
    const float bl0 = blin[2 * a], bl1 = blin[2 * a + 1];

    // act for row r0: sigmoid (a=0 -> i) or tanh = 2*sig(2v)-1 (a=1 -> g)
    const float inS  = a ? 2.0f : 1.0f;
    const float outS = a ? 2.0f : 1.0f;
    const float outB = a ? -1.0f : 0.0f;

    v2f c1 = splat2(0.0f), c2 = splat2(0.0f);
    sh1[tid] = 0.0f;
    sh2[tid] = 0.0f;

    const v4f* xp0 = reinterpret_cast<const v4f*>(x) + (size_t)b0 * T;
    const v4f* xp1 = reinterpret_cast<const v4f*>(x) + (size_t)b1 * T;
    v2f* op0 = reinterpret_cast<v2f*>(out + ((size_t)b0 * T) * 4 + 2 * a);
    v2f* op1 = reinterpret_cast<v2f*>(out + ((size_t)b1 * T) * 4 + 2 * a);
    const v4f* s1v = reinterpret_cast<const v4f*>(sh1);
    const v4f* s2v = reinterpret_cast<const v4f*>(sh2);

    v4f xa = xp0[0], xb = xp1[0];
    for (int t = 0; t < T; ++t) {
        const int tn = (t + 1 < T) ? (t + 1) : t;
        const v4f xa_n = xp0[tn], xb_n = xp1[tn];    // prefetch next x

        // ===== layer 1: A_r = Wih1[r]*x + Whh1[r]*h1_old + b, packed (e0,e1)
        v2f A0 = splat2(b1r0), A1 = splat2(b1r1);
        v2f A0b = splat2(0.0f), A1b = splat2(0.0f);
        A0 = fma2(splat2(wx0[0]), (v2f){xa.x, xb.x}, A0);
        A1 = fma2(splat2(wx1[0]), (v2f){xa.x, xb.x}, A1);
        A0 = fma2(splat2(wx0[1]), (v2f){xa.y, xb.y}, A0);
        A1 = fma2(splat2(wx1[1]), (v2f){xa.y, xb.y}, A1);
        A0b = fma2(splat2(wx0[2]), (v2f){xa.z, xb.z}, A0b);
        A1b = fma2(splat2(wx1[2]), (v2f){xa.z, xb.z}, A1b);
        A0b = fma2(splat2(wx0[3]), (v2f){xa.w, xb.w}, A0b);
        A1b = fma2(splat2(wx1[3]), (v2f){xa.w, xb.w}, A1b);
#pragma unroll
        for (int m = 0; m < 16; ++m) {
            const v4f u = s1v[m];                    // (k=2m: e0,e1 | k=2m+1: e0,e1)
            const v2f M0 = (v2f){u.x, u.y};
            const v2f M1 = (v2f){u.z, u.w};
            A0  = fma2(splat2(w1r0[2 * m]),     M0, A0);
            A1  = fma2(splat2(w1r1[2 * m]),     M0, A1);
            A0b = fma2(splat2(w1r0[2 * m + 1]), M1, A0b);
            A1b = fma2(splat2(w1r1[2 * m + 1]), M1, A1b);
        }
        const v2f Ar0 = A0 + A0b;                    // pre-act gate row r0 (e0,e1)
        const v2f Ar1 = A1 + A1b;                    // pre-act gate row r1
        v2f G0 = (v2f){fmaf(outS, sigf(inS * Ar0.x), outB),
                       fmaf(outS, sigf(inS * Ar0.y), outB)};   // i (a=0) / g (a=1)
        v2f G1 = (v2f){sigf(Ar1.x), sigf(Ar1.y)};              // f (a=0) / o (a=1)
        {
            const v2f P0 = shfl32_v2(G0);
            const v2f P1 = shfl32_v2(G1);
            const v2f iv = a ? P0 : G0;
            const v2f fv = a ? P1 : G1;
            const v2f gv = a ? G0 : P0;
            const v2f ov = a ? G1 : P1;
            c1 = fma2(fv, c1, iv * gv);              // identical in both halves
            const v2f h1n = ov * tanh_c2(c1);
            if (a == 0 && act)
                *reinterpret_cast<v2f*>(&sh1[2 * h]) = h1n;   // in-order DS pipe
        }

        // ===== layer 2: B_r = Wih2[r]*h1_new + Whh2[r]*h2_old + b
        v2f B0 = splat2(b2r0), B1 = splat2(b2r1);
        v2f B0b = splat2(0.0f), B1b = splat2(0.0f);
#pragma unroll
        for (int m = 0; m < 16; ++m) {
            const v4f v = s2v[m];                    // h2_old (read pre-update)
            const v2f N0 = (v2f){v.x, v.y};
            const v2f N1 = (v2f){v.z, v.w};
            B0  = fma2(splat2(wh0[2 * m]),      N0, B0);
            B1  = fma2(splat2(wh1_[2 * m]),     N0, B1);
            B0b = fma2(splat2(wh0[2 * m + 1]),  N1, B0b);
            B1b = fma2(splat2(wh1_[2 * m + 1]), N1, B1b);
        }
#pragma unroll
        for (int m = 0; m < 16; ++m) {
            const v4f u = s1v[m];                    // h1_new (after write above)
            const v2f M0 = (v2f){u.x, u.y};
            const v2f M1 = (v2f){u.z, u.w};
            B0  = fma2(splat2(wi0[2 * m]),     M0, B0);
            B1  = fma2(splat2(wi1[2 * m]),     M0, B1);
            B0b = fma2(splat2(wi0[2 * m + 1]), M1, B0b);
            B1b = fma2(splat2(wi1[2 * m + 1]), M1, B1b);
        }
        const v2f Br0 = B0 + B0b;
        const v2f Br1 = B1 + B1b;
        v2f H0 = (v2f){fmaf(outS, sigf(inS * Br0.x), outB),
                       fmaf(outS, sigf(inS * Br0.y), outB)};
        v2f H1 = (v2f){sigf(Br1.x), sigf(Br1.y)};
        v2f h2n;
        {
            const v2f P0 = shfl32_v2(H0);
            const v2f P1 = shfl32_v2(H1);
            const v2f iv = a ? P0 : H0;
            const v2f fv = a ? P1 : H1;
            const v2f gv = a ? H0 : P0;
            const v2f ov = a ? H1 : P1;
            c2 = fma2(fv, c2, iv * gv);
            h2n = ov * tanh_c2(c2);
            if (a == 0 && act)
                *reinterpret_cast<v2f*>(&sh2[2 * h]) = h2n;
        }

        // ===== head: out[e][o] = sum_h Wlin[o][h]*h2[e][h] + blin[o]
        // Half a owns outputs {2a, 2a+1}; DPP sum within each 32-half (VALU).
        const v2f Q0 = splat2(wlo0) * h2n;           // -> output 2a,   (e0,e1)
        const v2f Q1 = splat2(wlo1) * h2n;           // -> output 2a+1, (e0,e1)
        const float s0e0 = half_reduce(Q0.x), s0e1 = half_reduce(Q0.y);
        const float s1e0 = half_reduce(Q1.x), s1e1 = half_reduce(Q1.y);
        if ((tid & 31) == 31) {                      // lane31 (a=0) / lane63 (a=1)
            op0[2 * t] = (v2f){s0e0 + bl0, s1e0 + bl1};   // elem0, outputs 2a..2a+1
            op1[2 * t] = (v2f){s0e1 + bl0, s1e1 + bl1};   // elem1
        }
        xa = xa_n;
        xb = xb_n;
    }
}

extern "C" void kernel_launch(void* const* d_in, const int* in_sizes, int n_in,
                              void* d_out, int out_size, void* d_ws, size_t ws_size,
                              hipStream_t stream)
{
    const float* x    = (const float*)d_in[0];
    const float* Wih1 = (const float*)d_in[1];
    const float* bih1 = (const float*)d_in[2];
    const float* Whh1 = (const float*)d_in[3];
    const float* bhh1 = (const float*)d_in[4];
    const float* Wih2 = (const float*)d_in[5];
    const float* bih2 = (const float*)d_in[6];
    const float* Whh2 = (const float*)d_in[7];
    const float* bhh2 = (const float*)d_in[8];
    const float* Wlin = (const float*)d_in[9];
    const float* blin = (const float*)d_in[10];
    float* out = (float*)d_out;

    const int T = 1024;
    const int B = in_sizes[0] / (T * DIN);   // 2048

    hipLaunchKernelGGL(lstm2_kernel, dim3(B / 2), dim3(64), 0, stream,
                       x, Wih1, bih1, Whh1, bhh1, Wih2, bih2, Whh2, bhh2,
                       Wlin, blin, out, T);
}

// Round 6
// 1827.489 us; speedup vs baseline: 1.2698x; 1.2698x over previous
//
#include <hip/hip_runtime.h>

typedef float v2f __attribute__((ext_vector_type(2)));
typedef float v4f __attribute__((ext_vector_type(4)));

#define HH 30
#define DIN 4

__device__ __forceinline__ float sigf(float v) {
    return __builtin_amdgcn_rcpf(1.0f + __expf(-v));
}
__device__ __forceinline__ float tanhc(float c) {     // tanh(c) = 2*sig(2c)-1
    return fmaf(2.0f, sigf(2.0f * c), -1.0f);
}
__device__ __forceinline__ v2f fma2(v2f a, v2f b, v2f c) {
    return __builtin_elementwise_fma(a, b, c);
}
// DPP quad_perm (VALU pipe, 1 inst): all lanes active, old=src is a safe dummy.
template <int Ctrl>
__device__ __forceinline__ float qperm(float x) {
    union { float f; int i; } in, out;
    in.f = x;
    out.i = __builtin_amdgcn_update_dpp(in.i, in.i, Ctrl, 0xf, 0xf, false);
    return out.f;
}

// Two waves per block, ONE batch element per block.
// R2/R4/R5 evidence: per-lane weight demand >=130 floats always triggers the
// allocator's arch/acc split (arch VGPRs stop at 120-216, weights go to
// AGPR/scratch, +100% VALU inst). Fix: split the element across 2 waves so
// each lane owns ONE gate-row per matrix = 90 weight floats (total ~135 regs,
// comfortably arch-resident).
//   wave w (tid>>6) owns h-indices hg = 15*w + hl;  lane = 4*hl + g.
//   lane's rows: r = g*30+hg of Whh1 / Wih2 / Whh2 (15 v2f each) + Wih1 row.
// Each lane computes ONE gate preact (15 pk-FMA per matrix); activation type
// chosen by per-lane consts (g==2 -> tanh). Gates gathered inside the quad
// via DPP quad_perm (VALU, not DS). h1/h2 published through ping-pong LDS
// (2 __syncthreads per step, uniform control flow). Head: per-lane
// wl*h2 + 4x shfl_xor + 8-float LDS combine, finalized same iteration.
__global__ __attribute__((amdgpu_flat_work_group_size(128, 128)))
void lstm2_kernel(const float* __restrict__ x,
                  const float* __restrict__ Wih1, const float* __restrict__ bih1,
                  const float* __restrict__ Whh1, const float* __restrict__ bhh1,
                  const float* __restrict__ Wih2, const float* __restrict__ bih2,
                  const float* __restrict__ Whh2, const float* __restrict__ bhh2,
                  const float* __restrict__ Wlin, const float* __restrict__ blin,
                  float* __restrict__ out, int T)
{
    const int tid  = threadIdx.x;
    const int w    = tid >> 6;          // wave 0/1
    const int lane = tid & 63;
    const int g    = lane & 3;          // gate: 0=i 1=f 2=g 3=o
    const int hl   = lane >> 2;         // 0..15 (15 = pad)
    const bool act = (hl < 15);
    const int hlc  = act ? hl : 14;
    const int hg   = 15 * w + hlc;      // 0..29
    const int r    = g * HH + hg;       // gate-row of the 120-row stack
    const int b    = blockIdx.x;

    __shared__ __align__(16) float shA[2][32];   // h1 ping-pong
    __shared__ __align__(16) float shB[2][32];   // h2 ping-pong
    __shared__ float sp[2][8];                   // head partials (2 waves x 4 outs)

    // ---- per-lane weights: ONE row per matrix, packed v2f ----
    v2f w1[15], w2i[15], w2h[15];
#pragma unroll
    for (int k = 0; k < 15; ++k) {
        w1[k]  = (v2f){Whh1[r * HH + 2 * k], Whh1[r * HH + 2 * k + 1]};
        w2i[k] = (v2f){Wih2[r * HH + 2 * k], Wih2[r * HH + 2 * k + 1]};
        w2h[k] = (v2f){Whh2[r * HH + 2 * k], Whh2[r * HH + 2 * k + 1]};
    }
    v2f wxv[2];
    wxv[0] = (v2f){Wih1[r * DIN + 0], Wih1[r * DIN + 1]};
    wxv[1] = (v2f){Wih1[r * DIN + 2], Wih1[r * DIN + 3]};
    const float b1 = bih1[r] + bhh1[r];
    const float b2 = bih2[r] + bhh2[r];
    const float wl  = act ? Wlin[g * HH + hg] : 0.0f;   // output g, column hg
    const float blv = blin[g];

    // activation consts: sigmoid (1,1,0) for i/f/o, tanh=2*sig(2v)-1 (2,2,-1)
    const float inS  = (g == 2) ? 2.0f : 1.0f;
    const float outS = inS;
    const float outB = (g == 2) ? -1.0f : 0.0f;

    if (tid < 32) {
        shA[0][tid] = 0.0f; shA[1][tid] = 0.0f;
        shB[0][tid] = 0.0f; shB[1][tid] = 0.0f;
    }
    float c1 = 0.0f, c2 = 0.0f;

    const v4f* xp = reinterpret_cast<const v4f*>(x) + (size_t)b * T;
    float* op = out + (size_t)b * T * 4;

    v4f xc = xp[0];
    __syncthreads();

    for (int t = 0; t < T; ++t) {
        const int bw = t & 1, br = bw ^ 1;
        const v4f xn = xp[(t + 1 < T) ? (t + 1) : t];   // prefetch next x

        // ===== layer 1: preact = Wih1[r]·x + Whh1[r]·h1_old + b1 =====
        const v4f* hA = reinterpret_cast<const v4f*>(shA[br]);
        v2f A0 = (v2f){b1, 0.0f}, A1 = (v2f){0.0f, 0.0f};
        A0 = fma2(wxv[0], (v2f){xc.x, xc.y}, A0);
        A1 = fma2(wxv[1], (v2f){xc.z, xc.w}, A1);
#pragma unroll
        for (int j = 0; j < 8; ++j) {
            const v4f u = hA[j];
            A0 = fma2(w1[2 * j], (v2f){u.x, u.y}, A0);
            if (2 * j + 1 < 15)
                A1 = fma2(w1[2 * j + 1], (v2f){u.z, u.w}, A1);
        }
        const v2f As = A0 + A1;
        const float pre1 = As.x + As.y;
        const float av = fmaf(outS, sigf(inS * pre1), outB);
        // gather quad (on g0: av=i, +1=f, +2=g, +3=o); junk on g!=0 is bounded
        const float f1 = qperm<0x39>(av);    // lane+1
        const float g1 = qperm<0x4E>(av);    // lane+2
        const float o1 = qperm<0x93>(av);    // lane+3
        c1 = fmaf(f1, c1, av * g1);
        const float h1n = o1 * tanhc(c1);
        if (g == 0 && act) shA[bw][hg] = h1n;
        __syncthreads();

        // ===== layer 2: preact = Wih2[r]·h1_new + Whh2[r]·h2_old + b2 =====
        const v4f* hN = reinterpret_cast<const v4f*>(shA[bw]);
        const v4f* hO = reinterpret_cast<const v4f*>(shB[br]);
        v2f Ba = (v2f){b2, 0.0f}, Bb = (v2f){0.0f, 0.0f};
        v2f Bc = (v2f){0.0f, 0.0f}, Bd = (v2f){0.0f, 0.0f};
#pragma unroll
        for (int j = 0; j < 8; ++j) {
            const v4f u = hN[j];
            const v4f v = hO[j];
            Ba = fma2(w2i[2 * j], (v2f){u.x, u.y}, Ba);
            Bc = fma2(w2h[2 * j], (v2f){v.x, v.y}, Bc);
            if (2 * j + 1 < 15) {
                Bb = fma2(w2i[2 * j + 1], (v2f){u.z, u.w}, Bb);
                Bd = fma2(w2h[2 * j + 1], (v2f){v.z, v.w}, Bd);
            }
        }
        const v2f Bs = (Ba + Bb) + (Bc + Bd);
        const float pre2 = Bs.x + Bs.y;
        const float bv = fmaf(outS, sigf(inS * pre2), outB);
        const float f2 = qperm<0x39>(bv);
        const float g2 = qperm<0x4E>(bv);
        const float o2 = qperm<0x93>(bv);
        c2 = fmaf(f2, c2, bv * g2);
        const float h2n = o2 * tanhc(c2);
        if (g == 0 && act) shB[bw][hg] = h2n;

        // ===== head partial: out[g] += Wlin[g][hg] * h2[hg] =====
        const float hb = qperm<0x00>(h2n);   // broadcast quad's g0 value
        float p = wl * hb;                   // 0 on pad lanes
        p += __shfl_xor(p, 4, 64);
        p += __shfl_xor(p, 8, 64);
        p += __shfl_xor(p, 16, 64);
        p += __shfl_xor(p, 32, 64);          // sum over hl within this wave
        if (lane < 4) sp[bw][4 * w + lane] = p;
        __syncthreads();

        // ===== finalize out[b,t,:] (4 lanes) =====
        if (tid < 4) {
            op[t * 4 + tid] = sp[bw][tid] + sp[bw][4 + tid] + blv;
        }
        xc = xn;
    }
}

extern "C" void kernel_launch(void* const* d_in, const int* in_sizes, int n_in,
                              void* d_out, int out_size, void* d_ws, size_t ws_size,
                              hipStream_t stream)
{
    const float* x    = (const float*)d_in[0];
    const float* Wih1 = (const float*)d_in[1];
    const float* bih1 = (const float*)d_in[2];
    const float* Whh1 = (const float*)d_in[3];
    const float* bhh1 = (const float*)d_in[4];
    const float* Wih2 = (const float*)d_in[5];
    const float* bih2 = (const float*)d_in[6];
    const float* Whh2 = (const float*)d_in[7];
    const float* bhh2 = (const float*)d_in[8];
    const float* Wlin = (const float*)d_in[9];
    const float* blin = (const float*)d_in[10];
    float* out = (float*)d_out;

    const int T = 1024;
    const int B = in_sizes[0] / (T * DIN);   // 2048

    hipLaunchKernelGGL(lstm2_kernel, dim3(B), dim3(128), 0, stream,
                       x, Wih1, bih1, Whh1, bhh1, Wih2, bih2, Whh2, bhh2,
                       Wlin, blin, out, T);
}

// Round 7
// 1208.204 us; speedup vs baseline: 1.9207x; 1.5126x over previous
//
#include <hip/hip_runtime.h>

typedef float v2f __attribute__((ext_vector_type(2)));
typedef float v4f __attribute__((ext_vector_type(4)));

#define HH 30
#define DIN 4

// Forbid rematerialization: value becomes the output of an opaque asm, so the
// compiler must keep it live in a VGPR pair instead of re-loading from global
// every iteration (R2/R4/R5/R6 all showed VGPR_Count << weight footprint and
// ~2x the source VALU inst/step from reload+addr traffic).
#define PIN2(v) asm volatile("" : "+v"(v))

__device__ __forceinline__ float sigf(float v) {
    return __builtin_amdgcn_rcpf(1.0f + __expf(-v));
}
__device__ __forceinline__ v2f fma2(v2f a, v2f b, v2f c) {
    return __builtin_elementwise_fma(a, b, c);
}
__device__ __forceinline__ v2f splat2(float s) { return (v2f)s; }

// DPP reduce step on the VALU pipe (no DS occupancy), masked lanes add 0.
template <int Ctrl, int RowMask>
__device__ __forceinline__ float dpp_step(float x) {
    union { float f; int i; } in, out;
    in.f = x;
    out.i = __builtin_amdgcn_update_dpp(0, in.i, Ctrl, RowMask, 0xf, false);
    return x + out.f;
}
// lane31 = sum(lanes 0..31), lane63 = sum(lanes 32..63)
__device__ __forceinline__ float half_reduce(float x) {
    x = dpp_step<0x111, 0xf>(x);   // row_shr:1
    x = dpp_step<0x112, 0xf>(x);   // row_shr:2
    x = dpp_step<0x114, 0xf>(x);   // row_shr:4
    x = dpp_step<0x118, 0xf>(x);   // row_shr:8
    x = dpp_step<0x142, 0xa>(x);   // row_bcast:15 -> rows 1,3
    return x;
}

// One wave per block, one batch element per wave (R4 structure — best
// verified). a = lane>>5: a=0 owns (i,f) gate rows, a=1 owns (g,o); h=lane&31.
// Each lane: 2 gate rows of each matrix packed v2f (~94 pairs = 188 floats),
// PINNED into VGPRs via empty asm. 188 + ~45 working ≈ 235 regs < 256 arch
// cap; 2 waves/SIMD fit the 512-reg file -> waves_per_eu(2,2).
// h1/h2 broadcast via 32-float LDS (single-wave block: in-order DS, no
// barriers). Head reduced via DPP on the VALU pipe.
__global__ __attribute__((amdgpu_flat_work_group_size(64, 64),
                          amdgpu_waves_per_eu(2, 2)))
void lstm2_kernel(const float* __restrict__ x,
                  const float* __restrict__ Wih1, const float* __restrict__ bih1,
                  const float* __restrict__ Whh1, const float* __restrict__ bhh1,
                  const float* __restrict__ Wih2, const float* __restrict__ bih2,
                  const float* __restrict__ Whh2, const float* __restrict__ bhh2,
                  const float* __restrict__ Wlin, const float* __restrict__ blin,
                  float* __restrict__ out, int T)
{
    const int tid = threadIdx.x;
    const int a = tid >> 5;
    const int h = tid & 31;
    const bool act = (h < HH);
    const int hc = act ? h : (HH - 1);
    const int r0 = (2 * a) * HH + hc;
    const int r1 = (2 * a + 1) * HH + hc;
    const int b = blockIdx.x;

    __shared__ __align__(16) float sh1[32];
    __shared__ __align__(16) float sh2[32];

    // ---- per-lane packed weights, loaded once and PINNED ----
    v2f wx[DIN], wh1[HH], wi2[HH], wh2[HH];
#pragma unroll
    for (int c = 0; c < DIN; ++c) {
        wx[c] = (v2f){Wih1[r0 * DIN + c], Wih1[r1 * DIN + c]};
        PIN2(wx[c]);
    }
#pragma unroll
    for (int k = 0; k < HH; ++k) {
        wh1[k] = (v2f){Whh1[r0 * HH + k], Whh1[r1 * HH + k]};
        wi2[k] = (v2f){Wih2[r0 * HH + k], Wih2[r1 * HH + k]};
        wh2[k] = (v2f){Whh2[r0 * HH + k], Whh2[r1 * HH + k]};
        PIN2(wh1[k]);
        PIN2(wi2[k]);
        PIN2(wh2[k]);
    }
    v2f bias1 = (v2f){bih1[r0] + bhh1[r0], bih1[r1] + bhh1[r1]};
    v2f bias2 = (v2f){bih2[r0] + bhh2[r0], bih2[r1] + bhh2[r1]};
    v2f wlo = act ? (v2f){Wlin[(2 * a) * HH + hc], Wlin[(2 * a + 1) * HH + hc]}
                  : splat2(0.0f);
    v2f blv = (v2f){blin[2 * a], blin[2 * a + 1]};
    PIN2(bias1); PIN2(bias2); PIN2(wlo); PIN2(blv);

    // act0 = sigmoid (a=0: i) or tanh = 2*sig(2v)-1 (a=1: g)
    const float inS  = a ? 2.0f : 1.0f;
    const float outS = a ? 2.0f : 1.0f;
    const float outB = a ? -1.0f : 0.0f;

    float c1 = 0.0f, c2 = 0.0f;
    sh1[h] = 0.0f;
    sh2[h] = 0.0f;

    const v4f* xp = reinterpret_cast<const v4f*>(x) + (size_t)b * T;
    v2f* op = reinterpret_cast<v2f*>(out) + (size_t)b * T * 2 + a;
    const v4f* s1v = reinterpret_cast<const v4f*>(sh1);
    const v4f* s2v = reinterpret_cast<const v4f*>(sh2);

    v4f xc = xp[0];
    for (int t = 0; t < T; ++t) {
        const v4f xn = xp[(t + 1 < T) ? (t + 1) : t];   // prefetch next x

        // ===== layer 1: gates = Wih1*x + Whh1*h1_old + b (2 chains) =====
        v2f A0 = bias1, A1 = splat2(0.0f);
        A0 = fma2(wx[0], splat2(xc.x), A0);
        A0 = fma2(wx[1], splat2(xc.y), A0);
        A0 = fma2(wx[2], splat2(xc.z), A0);
        A0 = fma2(wx[3], splat2(xc.w), A0);
#pragma unroll
        for (int j = 0; j < 7; ++j) {
            const v4f u = s1v[j];
            if (j & 1) {
                A1 = fma2(wh1[4 * j + 0], splat2(u.x), A1);
                A1 = fma2(wh1[4 * j + 1], splat2(u.y), A1);
                A1 = fma2(wh1[4 * j + 2], splat2(u.z), A1);
                A1 = fma2(wh1[4 * j + 3], splat2(u.w), A1);
            } else {
                A0 = fma2(wh1[4 * j + 0], splat2(u.x), A0);
                A0 = fma2(wh1[4 * j + 1], splat2(u.y), A0);
                A0 = fma2(wh1[4 * j + 2], splat2(u.z), A0);
                A0 = fma2(wh1[4 * j + 3], splat2(u.w), A0);
            }
        }
        {
            const v4f u = s1v[7];
            A1 = fma2(wh1[28], splat2(u.x), A1);
            A1 = fma2(wh1[29], splat2(u.y), A1);
        }
        const v2f A = A0 + A1;
        float a0 = fmaf(outS, sigf(inS * A.x), outB);    // i (a=0) / g (a=1)
        float a1 = sigf(A.y);                            // f (a=0) / o (a=1)
        const float p0 = __shfl_xor(a0, 32, 64);
        const float p1 = __shfl_xor(a1, 32, 64);
        const float iv = a ? p0 : a0;
        const float fv = a ? p1 : a1;
        const float gv = a ? a0 : p0;
        const float ov = a ? a1 : p1;
        c1 = fmaf(fv, c1, iv * gv);                      // identical in both halves
        const float h1n = ov * fmaf(2.0f, sigf(2.0f * c1), -1.0f);
        sh1[h] = h1n;

        // ===== layer 2: Whh2*h2_old first (independent of sh1 write) =====
        v2f Bc = splat2(0.0f), Bd = splat2(0.0f);
#pragma unroll
        for (int j = 0; j < 7; ++j) {
            const v4f v = s2v[j];
            if (j & 1) {
                Bd = fma2(wh2[4 * j + 0], splat2(v.x), Bd);
                Bd = fma2(wh2[4 * j + 1], splat2(v.y), Bd);
                Bd = fma2(wh2[4 * j + 2], splat2(v.z), Bd);
                Bd = fma2(wh2[4 * j + 3], splat2(v.w), Bd);
            } else {
                Bc = fma2(wh2[4 * j + 0], splat2(v.x), Bc);
                Bc = fma2(wh2[4 * j + 1], splat2(v.y), Bc);
                Bc = fma2(wh2[4 * j + 2], splat2(v.z), Bc);
                Bc = fma2(wh2[4 * j + 3], splat2(v.w), Bc);
            }
        }
        {
            const v4f v = s2v[7];
            Bd = fma2(wh2[28], splat2(v.x), Bd);
            Bd = fma2(wh2[29], splat2(v.y), Bd);
        }
        v2f Ba = bias2, Bb = splat2(0.0f);
#pragma unroll
        for (int j = 0; j < 7; ++j) {
            const v4f u = s1v[j];                        // h1_new (DS in-order)
            if (j & 1) {
                Bb = fma2(wi2[4 * j + 0], splat2(u.x), Bb);
                Bb = fma2(wi2[4 * j + 1], splat2(u.y), Bb);
                Bb = fma2(wi2[4 * j + 2], splat2(u.z), Bb);
                Bb = fma2(wi2[4 * j + 3], splat2(u.w), Bb);
            } else {
                Ba = fma2(wi2[4 * j + 0], splat2(u.x), Ba);
                Ba = fma2(wi2[4 * j + 1], splat2(u.y), Ba);
                Ba = fma2(wi2[4 * j + 2], splat2(u.z), Ba);
                Ba = fma2(wi2[4 * j + 3], splat2(u.w), Ba);
            }
        }
        {
            const v4f u = s1v[7];
            Bb = fma2(wi2[28], splat2(u.x), Bb);
            Bb = fma2(wi2[29], splat2(u.y), Bb);
        }
        const v2f Bv = (Ba + Bb) + (Bc + Bd);
        a0 = fmaf(outS, sigf(inS * Bv.x), outB);
        a1 = sigf(Bv.y);
        const float q0 = __shfl_xor(a0, 32, 64);
        const float q1 = __shfl_xor(a1, 32, 64);
        const float iv2 = a ? q0 : a0;
        const float fv2 = a ? q1 : a1;
        const float gv2 = a ? a0 : q0;
        const float ov2 = a ? a1 : q1;
        c2 = fmaf(fv2, c2, iv2 * gv2);
        const float h2n = ov2 * fmaf(2.0f, sigf(2.0f * c2), -1.0f);
        sh2[h] = h2n;

        // ===== head: out = Wlin @ h2 + b via DPP (VALU pipe) =====
        const v2f pv = wlo * splat2(h2n);                // 0 on pad lanes
        const float rx = half_reduce(pv.x);
        const float ry = half_reduce(pv.y);
        if ((tid & 31) == 31) {                          // lane31 (a=0) / lane63 (a=1)
            op[2 * t] = (v2f){rx + blv.x, ry + blv.y};
        }
        xc = xn;
    }
}

extern "C" void kernel_launch(void* const* d_in, const int* in_sizes, int n_in,
                              void* d_out, int out_size, void* d_ws, size_t ws_size,
                              hipStream_t stream)
{
    const float* x    = (const float*)d_in[0];
    const float* Wih1 = (const float*)d_in[1];
    const float* bih1 = (const float*)d_in[2];
    const float* Whh1 = (const float*)d_in[3];
    const float* bhh1 = (const float*)d_in[4];
    const float* Wih2 = (const float*)d_in[5];
    const float* bih2 = (const float*)d_in[6];
    const float* Whh2 = (const float*)d_in[7];
    const float* bhh2 = (const float*)d_in[8];
    const float* Wlin = (const float*)d_in[9];
    const float* blin = (const float*)d_in[10];
    float* out = (float*)d_out;

    const int T = 1024;
    const int B = in_sizes[0] / (T * DIN);   // 2048

    hipLaunchKernelGGL(lstm2_kernel, dim3(B), dim3(64), 0, stream,
                       x, Wih1, bih1, Whh1, bhh1, Wih2, bih2, Whh2, bhh2,
                       Wlin, blin, out, T);
}